// Round 3
// baseline (193.039 us; speedup 1.0000x reference)
//
#include <hip/hip_runtime.h>
#include <hip/hip_bf16.h>

#define B_ 2
#define T_ 2048
#define C_ 1024
#define H_ 16
#define D_ 64

typedef unsigned short u16;
typedef __bf16 bf16x8 __attribute__((ext_vector_type(8)));
typedef float floatx4 __attribute__((ext_vector_type(4)));

__device__ __forceinline__ float bf2f(u16 u) {
  union { unsigned int i; float f; } x; x.i = ((unsigned int)u) << 16; return x.f;
}
__device__ __forceinline__ u16 f2bf(float f) {  // RNE
  union { float f; unsigned int i; } x; x.f = f;
  unsigned int r = x.i + 0x7fffu + ((x.i >> 16) & 1u);
  return (u16)(r >> 16);
}

// packed f32x2 -> bf16x2 (RTNE), lo = src0
__device__ __forceinline__ unsigned cvtpk(float lo, float hi) {
  unsigned r;
  asm("v_cvt_pk_bf16_f32 %0, %1, %2" : "=v"(r) : "v"(lo), "v"(hi));
  return r;
}

// async 16B global -> LDS (wave-uniform base + lane*16)
__device__ __forceinline__ void gld16(void* lds, const void* g) {
  __builtin_amdgcn_global_load_lds(
      (const __attribute__((address_space(1))) unsigned int*)g,
      (__attribute__((address_space(3))) unsigned int*)lds, 16, 0, 0);
}

// ---------------------------------------------------------------------------
// Fused fp32 -> bf16 convert for x + 4 weights (one dispatch).
// ---------------------------------------------------------------------------
#define NXF4 1048576   // (B*T*C)/4
#define NWF4 262144    // (C*C)/4

__global__ __launch_bounds__(256) void cvt_all(
    const float* __restrict__ x,  const float* __restrict__ Wq,
    const float* __restrict__ Wk, const float* __restrict__ Wv,
    const float* __restrict__ Wo, u16* __restrict__ dst_base)
{
  const int i = blockIdx.x * 256 + threadIdx.x;
  const float* src; size_t off;
  if (i < NXF4)               { src = x;  off = i; }
  else if (i < NXF4 + NWF4)   { src = Wq; off = i - NXF4; }
  else if (i < NXF4 + 2*NWF4) { src = Wk; off = i - (NXF4 + NWF4); }
  else if (i < NXF4 + 3*NWF4) { src = Wv; off = i - (NXF4 + 2*NWF4); }
  else                        { src = Wo; off = i - (NXF4 + 3*NWF4); }
  float4 f = ((const float4*)src)[off];
  ushort4 o;
  o.x = f2bf(f.x); o.y = f2bf(f.y); o.z = f2bf(f.z); o.w = f2bf(f.w);
  ((ushort4*)dst_base)[i] = o;
}

// ---------------------------------------------------------------------------
// Fused QKV GEMM, 256x256 tile, BK=64, 8-phase counted-vmcnt schedule
// (T1 XCD-partition + T2 XOR-swizzle + T3/T4 8-phase counted vmcnt + T5
//  setprio). One N=3072 GEMM; each 256-wide N-tile lies entirely inside
//  Q (by 0-3), K (by 4-7) or V (by 8-11).
// ---------------------------------------------------------------------------
#define QSCALE 0.1803368801111f  // 0.125 / ln(2)

#define MFMA16(MH, NH, BREG)                                                  \
  do {                                                                        \
    __builtin_amdgcn_s_setprio(1);                                            \
    _Pragma("unroll")                                                         \
    for (int f = 0; f < 4; ++f) {                                             \
      _Pragma("unroll")                                                       \
      for (int g = 0; g < 2; ++g) {                                           \
        acc[(MH)*4 + f][(NH)*2 + g] = __builtin_amdgcn_mfma_f32_16x16x32_bf16(\
            a[f][0], BREG[g][0], acc[(MH)*4 + f][(NH)*2 + g], 0, 0, 0);       \
        acc[(MH)*4 + f][(NH)*2 + g] = __builtin_amdgcn_mfma_f32_16x16x32_bf16(\
            a[f][1], BREG[g][1], acc[(MH)*4 + f][(NH)*2 + g], 0, 0, 0);       \
      }                                                                       \
    }                                                                         \
    __builtin_amdgcn_s_setprio(0);                                            \
  } while (0)

#define PBAR()                                                \
  do {                                                        \
    asm volatile("" ::: "memory");                            \
    __builtin_amdgcn_s_barrier();                             \
    asm volatile("s_waitcnt lgkmcnt(0)" ::: "memory");        \
  } while (0)

#define EBAR()                                                \
  do {                                                        \
    asm volatile("" ::: "memory");                            \
    __builtin_amdgcn_s_barrier();                             \
    asm volatile("" ::: "memory");                            \
  } while (0)

__global__ __launch_bounds__(512, 2) void gemm_qkv8(
    const u16* __restrict__ X, const u16* __restrict__ Wb,
    const float* __restrict__ b0, const float* __restrict__ b1,
    const float* __restrict__ b2,
    u16* __restrict__ Yq, u16* __restrict__ Yk, u16* __restrict__ Yv)
{
  __shared__ __align__(16) u16 L[65536];  // 128 KiB

  const int tid  = threadIdx.x;
  const int lane = tid & 63;
  const int m16  = lane & 15;
  const int q4   = lane >> 4;
  const int wv   = tid >> 6;
  const int wm   = wv >> 2;   // 0..1 : A-half / 128-row slab
  const int wn   = wv & 3;    // 0..3 : 64-col slab

  // XCD-bijective mapping: xcd = bid%8 (round-robin dispatch); each XCD
  // owns a 4x6 (bx,by) sub-grid -> A 2MB + B 3MB working set per L2.
  const int bid = blockIdx.x;
  const int xcd = bid & 7;
  const int idx = bid >> 3;            // 0..23
  const int bx  = (xcd & 3) * 4 + (idx & 3);   // 0..15
  const int by  = (xcd >> 2) * 6 + (idx >> 2); // 0..11

  const u16* Abase  = X  + (size_t)bx * 256 * C_;
  const u16* Bbase  = Wb + (size_t)by * 256 * C_;
  const u16* A1base = Abase + (size_t)128 * C_;
  const u16* B1base = Bbase + (size_t)128 * C_;

  // staging decomposition: phys byte = s*16, s = r*512+tid; row=s>>3,
  // slot16=s&7; content k16 = slot16 ^ (row&7)  (pre-swizzled source)
  const int s0 = tid,       r0 = s0 >> 3;
  const int s1 = tid + 512, r1 = s1 >> 3;
  const int k0a = ((s0 & 7) ^ (r0 & 7)) * 8;
  const int k1a = ((s1 & 7) ^ (r1 & 7)) * 8;

#define STAGE(dsthalf, srcrows, kofs)                                         \
  do {                                                                        \
    gld16(&(dsthalf)[s0 * 8], (srcrows) + (size_t)r0 * C_ + (kofs) + k0a);    \
    gld16(&(dsthalf)[s1 * 8], (srcrows) + (size_t)r1 * C_ + (kofs) + k1a);    \
  } while (0)

  u16* buf0 = L;
  u16* buf1 = L + 32768;
  // half offsets (u16): A0=0  A1=8192  B0=16384  B1=24576

  // prologue: T0 complete + T1{B0,A0} in flight
  STAGE(buf0 + 16384, Bbase, 0);
  STAGE(buf0,         Abase, 0);
  STAGE(buf0 + 24576, B1base, 0);
  STAGE(buf0 + 8192,  A1base, 0);
  STAGE(buf1 + 16384, Bbase, 64);
  STAGE(buf1,         Abase, 64);
  asm volatile("s_waitcnt vmcnt(4)" ::: "memory");
  __builtin_amdgcn_s_barrier();
  asm volatile("" ::: "memory");

  floatx4 acc[8][4] = {};

  // ds_read swizzled k-slot offsets (row&7 == lane&7 for all frag rows)
  const int a0off = m16 * 64 + ((q4      ^ (lane & 7)) * 8);  // k-chunk 0
  const int a1off = m16 * 64 + (((q4 + 4) ^ (lane & 7)) * 8); // k-chunk 1
  const int bro   = (wn & 1) * 4096;  // row offset inside wave's B-half

  for (int i = 0; i < 16; ++i) {
    u16* buf  = (i & 1) ? buf1 : buf0;
    u16* bufn = (i & 1) ? buf0 : buf1;
    const u16* Ah = buf + wm * 8192;
    const u16* Bh = buf + 16384 + (wn >> 1) * 8192;
    const bool p1 = (i + 1) < 16;
    const bool p2 = (i + 2) < 16;
    const int  k1 = (i + 1) * 64;
    const int  k2 = (i + 2) * 64;

    bf16x8 a[4][2], bA[2][2], bB[2][2];

    // ---- phase 0: (mh0, nh0) — 12 ds_reads ----
#pragma unroll
    for (int f = 0; f < 4; ++f) {
      a[f][0] = *(const bf16x8*)&Ah[f * 1024 + a0off];
      a[f][1] = *(const bf16x8*)&Ah[f * 1024 + a1off];
    }
#pragma unroll
    for (int g = 0; g < 2; ++g) {
      bA[g][0] = *(const bf16x8*)&Bh[bro + g * 1024 + a0off];
      bA[g][1] = *(const bf16x8*)&Bh[bro + g * 1024 + a1off];
    }
    if (p1) STAGE(bufn + 24576, B1base, k1);
    PBAR();
    MFMA16(0, 0, bA);
    EBAR();

    // ---- phase 1: (mh0, nh1) — 4 ds_reads ----
#pragma unroll
    for (int g = 0; g < 2; ++g) {
      bB[g][0] = *(const bf16x8*)&Bh[bro + 2048 + g * 1024 + a0off];
      bB[g][1] = *(const bf16x8*)&Bh[bro + 2048 + g * 1024 + a1off];
    }
    if (p1) STAGE(bufn + 8192, A1base, k1);
    PBAR();
    MFMA16(0, 1, bB);
    EBAR();

    // ---- phase 2: (mh1, nh1) — 8 ds_reads ----
#pragma unroll
    for (int f = 0; f < 4; ++f) {
      a[f][0] = *(const bf16x8*)&Ah[4096 + f * 1024 + a0off];
      a[f][1] = *(const bf16x8*)&Ah[4096 + f * 1024 + a1off];
    }
    if (p2) STAGE(buf + 16384, Bbase, k2);   // B reads of this tile done
    PBAR();
    MFMA16(1, 1, bB);
    EBAR();

    // ---- phase 3: (mh1, nh0) — no ds_reads ----
    if (p2) STAGE(buf, Abase, k2);           // A reads of this tile done
    PBAR();
    MFMA16(1, 0, bA);
    asm volatile("" ::: "memory");
    if (p2) asm volatile("s_waitcnt vmcnt(4)" ::: "memory");
    else    asm volatile("s_waitcnt vmcnt(0)" ::: "memory");
    __builtin_amdgcn_s_barrier();
    asm volatile("" ::: "memory");
  }

  // ---- epilogue ----
  const int z    = by >> 2;                       // 0=Q 1=K 2=V
  const int nloc = (by & 3) * 256 + wn * 64;      // n within the z-matrix
  const float* bias = (z == 0) ? b0 : (z == 1) ? b1 : b2;
  const int mbase = bx * 256 + wm * 128 + q4 * 4;

  if (z == 2) {
    // V -> [B,H,D,T]; 4 consecutive t per thread => ushort4 stores
#pragma unroll
    for (int nf = 0; nf < 4; ++nf) {
      const int nz = nloc + nf * 16 + m16;
      const float bv = bias[nz];
      const int h = nz >> 6, d = nz & (D_ - 1);
#pragma unroll
      for (int mf = 0; mf < 8; ++mf) {
        const int m  = mbase + mf * 16;
        const int bb = m >> 11, t = m & (T_ - 1);
        ushort4 pk;
        pk.x = f2bf(acc[mf][nf][0] + bv);
        pk.y = f2bf(acc[mf][nf][1] + bv);
        pk.z = f2bf(acc[mf][nf][2] + bv);
        pk.w = f2bf(acc[mf][nf][3] + bv);
        *(ushort4*)&Yv[(((size_t)bb * H_ + h) * D_ + d) * T_ + t] = pk;
      }
    }
  } else {
    // Q/K -> [B,H,T,D]
    u16* Y = z ? Yk : Yq;
    const float sc = z ? 1.0f : QSCALE;
#pragma unroll
    for (int nf = 0; nf < 4; ++nf) {
      const int nz = nloc + nf * 16 + m16;
      const float bv = bias[nz];
      const int h = nz >> 6, d = nz & (D_ - 1);
#pragma unroll
      for (int mf = 0; mf < 8; ++mf) {
        const int m  = mbase + mf * 16;
        const int bb = m >> 11, tq = m & (T_ - 1);
#pragma unroll
        for (int r = 0; r < 4; ++r) {
          Y[(((size_t)bb * H_ + h) * T_ + (tq + r)) * D_ + d] =
              f2bf((acc[mf][nf][r] + bv) * sc);
        }
      }
    }
  }
}

// ---------------------------------------------------------------------------
// Output projection GEMM (round-7 proven): 128x64 tile, BK=32, 512 blocks.
// ---------------------------------------------------------------------------
__global__ __launch_bounds__(256) void gemm_out(
    const u16* __restrict__ X, const u16* __restrict__ W,
    const float* __restrict__ bias, float* __restrict__ Yf)
{
  const int K = C_, N = C_;
  __shared__ __align__(16) u16 As[128 * 32];  // 8 KB
  __shared__ __align__(16) u16 Bs[64 * 32];   // 4 KB

  const int tid  = threadIdx.x;
  const int wv   = tid >> 6;
  const int lane = tid & 63;
  const int mcol = lane & 15;
  const int quad = lane >> 4;
  const int wr = wv >> 1, wc = wv & 1;
  const int m0 = blockIdx.x * 128;
  const int n0 = blockIdx.y * 64;

  const int srow = tid >> 2;
  const int scol = (tid & 3) * 8;
  const u16* xp0 = X + (size_t)(m0 + srow) * K + scol;
  const u16* xp1 = xp0 + (size_t)64 * K;
  const u16* wp  = W + (size_t)(n0 + srow) * K + scol;

  floatx4 acc[4][2] = {};

  for (int k0 = 0; k0 < K; k0 += 32) {
    gld16(&As[tid * 8],        xp0 + k0);
    gld16(&As[2048 + tid * 8], xp1 + k0);
    gld16(&Bs[tid * 8],        wp + k0);
    __syncthreads();

    bf16x8 a[4], b[2];
#pragma unroll
    for (int rf = 0; rf < 4; ++rf)
      a[rf] = *(const bf16x8*)&As[(wr * 64 + rf * 16 + mcol) * 32 + quad * 8];
#pragma unroll
    for (int cf = 0; cf < 2; ++cf)
      b[cf] = *(const bf16x8*)&Bs[(wc * 32 + cf * 16 + mcol) * 32 + quad * 8];
#pragma unroll
    for (int rf = 0; rf < 4; ++rf)
#pragma unroll
      for (int cf = 0; cf < 2; ++cf)
        acc[rf][cf] = __builtin_amdgcn_mfma_f32_16x16x32_bf16(
            a[rf], b[cf], acc[rf][cf], 0, 0, 0);
    __syncthreads();
  }

#pragma unroll
  for (int cf = 0; cf < 2; ++cf) {
    const int n = n0 + wc * 32 + cf * 16 + mcol;
    const float bv = bias[n];
#pragma unroll
    for (int rf = 0; rf < 4; ++rf) {
#pragma unroll
      for (int r = 0; r < 4; ++r) {
        const int m = m0 + wr * 64 + rf * 16 + quad * 4 + r;
        Yf[(size_t)m * N + n] = acc[rf][cf][r] + bv;
      }
    }
  }
}

// ---------------------------------------------------------------------------
// MFMA flash attention, causal, fixed-base softmax (log2 domain), l via
// ones-row MFMA, K/V double-buffered, swapped QK^T + in-register P rebuild
// (cvt_pk + permlane chain).
//
// This revision: QBLK 64 -> 128 per block (each wave owns 32 q-rows in two
// 16-row halves sharing the same K/V fragment reads). Rationale: round-1/2
// counters showed no pipe saturated (MfmaUtil 15, VALU 45, LDS ~40%) =>
// dependency-chain bound. Doubling q per wave gives each wave two
// independent QK->softmax->PV chains per K/V read: 18 ds_read_b128 now
// feed 36 MFMAs, block-iters drop 16896->8704, LDS traffic and barrier
// count per unit work halve.
//
// Grid 512 (32 heads x 16 q-tiles of 128 rows), XCD invariant bh = bx&31.
// Balanced iq map: g = bx>>5, iq = g<8 ? 15-g : g-8  => the two blocks
// co-resident on a CU (bx, bx+256) sum to 34 iters; big tiles first.
// Causal mask on last two k-tiles: dj = j-2*iq in {0,1},
//   klim = wv*32 + half*16 + m16 - dj*64; mask k_local > klim.
// ---------------------------------------------------------------------------
#define KSB 4096   // u16 elems per Ks buffer (64*64)
#define VTB 5120   // u16 elems per Vt buffer (80*64; rows 64..79 = ones/zeros)

__global__ __launch_bounds__(256, 2) void attn_flash(
    const u16* __restrict__ Q, const u16* __restrict__ K,
    const u16* __restrict__ Vg, u16* __restrict__ O)
{
  __shared__ __align__(16) u16 Ks[2 * KSB];     // 16 KB
  __shared__ __align__(16) u16 Vt[2 * VTB];     // 20 KB

  const int tid  = threadIdx.x;
  const int wv   = tid >> 6;
  const int lane = tid & 63;
  const int mcol = lane & 15;
  const int quad = lane >> 4;

  const int bx = blockIdx.x;
  const int bh = bx & 31;             // XCD-partition invariant
  const int g  = bx >> 5;             // 0..15
  const int iq = (g < 8) ? 15 - g : g - 8;   // balanced: per-CU sum 15
  const size_t base  = (size_t)bh * T_ * D_;
  const size_t vbase = (size_t)bh * D_ * T_;
  const int b = bh >> 4, h = bh & (H_ - 1);

  // ones rows in BOTH Vt buffers (rows 64..79; staging only touches 0..63)
  for (int idx = tid; idx < 16 * 64; idx += 256) {
    const u16 val = (idx < 64) ? (u16)0x3F80 : (u16)0;
    Vt[64 * 64 + idx]       = val;
    Vt[VTB + 64 * 64 + idx] = val;
  }

  const int srow = lane >> 3;
  const int sg   = (lane & 7) ^ srow;
  const int c0 = wv * 2, c1 = wv * 2 + 1;
  const int sl0 = (quad ^ (mcol & 7)) * 8;

  const size_t koff0 = base + (size_t)(c0 * 8 + srow) * D_ + sg * 8;
  const size_t koff1 = base + (size_t)(c1 * 8 + srow) * D_ + sg * 8;
  const size_t voff0 = vbase + (size_t)(c0 * 8 + srow) * T_ + sg * 8;
  const size_t voff1 = vbase + (size_t)(c1 * 8 + srow) * T_ + sg * 8;

  // 32 q-rows per wave: halves at rows wv*32 + {0,16} + m16
  const u16* qg = Q + base + (size_t)(iq * 128 + wv * 32 + mcol) * D_ + quad * 8;
  const bf16x8 qf[2][2] = {
    { *(const bf16x8*)qg,               *(const bf16x8*)(qg + 32) },
    { *(const bf16x8*)(qg + 16 * D_),   *(const bf16x8*)(qg + 16 * D_ + 32) }
  };

  floatx4 oacc[2][5] = {};   // [half][0..3] D-cols; [half][4] rowsum

  const int nj = 2 * iq + 1;  // last k-tile index

  // ones-row init visible to all waves, then stage j=0 into buffer 0
  __syncthreads();
  gld16(&Ks[c0 * 512 + lane * 8], K  + koff0);
  gld16(&Ks[c1 * 512 + lane * 8], K  + koff1);
  gld16(&Vt[c0 * 512 + lane * 8], Vg + voff0);
  gld16(&Vt[c1 * 512 + lane * 8], Vg + voff1);

  for (int j = 0; j <= nj; ++j) {
    const int cur = j & 1;
    __syncthreads();   // drains vmcnt(0): buffer `cur` ready

    if (j < nj) {      // prefetch j+1 into the other buffer
      const int nb = cur ^ 1;
      const size_t kj = (size_t)(j + 1) * 64 * D_;
      const int    vj = (j + 1) * 64;
      gld16(&Ks[nb * KSB + c0 * 512 + lane * 8], K  + koff0 + kj);
      gld16(&Ks[nb * KSB + c1 * 512 + lane * 8], K  + koff1 + kj);
      gld16(&Vt[nb * VTB + c0 * 512 + lane * 8], Vg + voff0 + vj);
      gld16(&Vt[nb * VTB + c1 * 512 + lane * 8], Vg + voff1 + vj);
    }

    const u16* ksb = &Ks[cur * KSB];
    const u16* vtb = &Vt[cur * VTB];

    // SWAPPED QK^T: sacc[half][nt][r] = S[q = mcol (+half*16)][
    // k = nt*16 + quad*4 + r]. K frags read once, used by both halves.
    floatx4 sacc[2][4] = {};
    __builtin_amdgcn_s_setprio(1);
#pragma unroll
    for (int nt = 0; nt < 4; ++nt) {
      const u16* kr = &ksb[(nt * 16 + mcol) * 64];
      bf16x8 kb0 = *(const bf16x8*)&kr[sl0];
      bf16x8 kb1 = *(const bf16x8*)&kr[sl0 ^ 32];
      sacc[0][nt] = __builtin_amdgcn_mfma_f32_16x16x32_bf16(kb0, qf[0][0], sacc[0][nt], 0, 0, 0);
      sacc[0][nt] = __builtin_amdgcn_mfma_f32_16x16x32_bf16(kb1, qf[0][1], sacc[0][nt], 0, 0, 0);
      sacc[1][nt] = __builtin_amdgcn_mfma_f32_16x16x32_bf16(kb0, qf[1][0], sacc[1][nt], 0, 0, 0);
      sacc[1][nt] = __builtin_amdgcn_mfma_f32_16x16x32_bf16(kb1, qf[1][1], sacc[1][nt], 0, 0, 0);
    }
    __builtin_amdgcn_s_setprio(0);

    const int dj = j - 2 * iq;
    if (dj >= 0) {     // causal mask on the last two k-tiles
#pragma unroll
      for (int hf = 0; hf < 2; ++hf) {
        const int klim = wv * 32 + hf * 16 + mcol - dj * 64;
#pragma unroll
        for (int nt = 0; nt < 4; ++nt)
#pragma unroll
          for (int r = 0; r < 4; ++r)
            if (nt * 16 + quad * 4 + r > klim) sacc[hf][nt][r] = -1e30f;
      }
    }

    // exp2 + pack + in-register redistribute -> PV A-frags (per half)
    bf16x8 pa[2][2];
#pragma unroll
    for (int hf = 0; hf < 2; ++hf) {
      unsigned w[4][2];
#pragma unroll
      for (int nt = 0; nt < 4; ++nt)
#pragma unroll
        for (int i = 0; i < 2; ++i)
          w[nt][i] = cvtpk(exp2f(sacc[hf][nt][2*i]), exp2f(sacc[hf][nt][2*i+1]));
      union { unsigned u[4]; bf16x8 v; } p0, p1;
#pragma unroll
      for (int i = 0; i < 2; ++i) {
        unsigned x = w[0][i], y = w[1][i];
        asm("v_permlane32_swap_b32 %0, %1" : "+v"(x), "+v"(y));
        asm("v_permlane16_swap_b32 %0, %1" : "+v"(x), "+v"(y));
        p0.u[i] = x; p0.u[i + 2] = y;
        unsigned x2 = w[2][i], y2 = w[3][i];
        asm("v_permlane32_swap_b32 %0, %1" : "+v"(x2), "+v"(y2));
        asm("v_permlane16_swap_b32 %0, %1" : "+v"(x2), "+v"(y2));
        p1.u[i] = x2; p1.u[i + 2] = y2;
      }
      pa[hf][0] = p0.v; pa[hf][1] = p1.v;
    }

    __builtin_amdgcn_s_setprio(1);
#pragma unroll
    for (int dt = 0; dt < 5; ++dt) {
      const u16* vr = &vtb[(dt * 16 + mcol) * 64];
      bf16x8 vb0 = *(const bf16x8*)&vr[sl0];
      bf16x8 vb1 = *(const bf16x8*)&vr[sl0 ^ 32];
      oacc[0][dt] = __builtin_amdgcn_mfma_f32_16x16x32_bf16(pa[0][0], vb0, oacc[0][dt], 0, 0, 0);
      oacc[0][dt] = __builtin_amdgcn_mfma_f32_16x16x32_bf16(pa[0][1], vb1, oacc[0][dt], 0, 0, 0);
      oacc[1][dt] = __builtin_amdgcn_mfma_f32_16x16x32_bf16(pa[1][0], vb0, oacc[1][dt], 0, 0, 0);
      oacc[1][dt] = __builtin_amdgcn_mfma_f32_16x16x32_bf16(pa[1][1], vb1, oacc[1][dt], 0, 0, 0);
    }
    __builtin_amdgcn_s_setprio(0);
  }

#pragma unroll
  for (int hf = 0; hf < 2; ++hf) {
    float invl[4];
#pragma unroll
    for (int r = 0; r < 4; ++r)
      invl[r] = 1.f / __shfl(oacc[hf][4][r], lane & 48);
#pragma unroll
    for (int dt = 0; dt < 4; ++dt) {
      const int c = h * D_ + dt * 16 + mcol;
#pragma unroll
      for (int r = 0; r < 4; ++r) {
        const int t = iq * 128 + wv * 32 + hf * 16 + quad * 4 + r;
        O[((size_t)b * T_ + t) * C_ + c] = f2bf(oacc[hf][dt][r] * invl[r]);
      }
    }
  }
}

// ---------------------------------------------------------------------------
extern "C" void kernel_launch(void* const* d_in, const int* in_sizes, int n_in,
                              void* d_out, int out_size, void* d_ws, size_t ws_size,
                              hipStream_t stream) {
  const float* x  = (const float*)d_in[0];
  const float* Wq = (const float*)d_in[1];
  const float* bq = (const float*)d_in[2];
  const float* Wk = (const float*)d_in[3];
  const float* bk = (const float*)d_in[4];
  const float* Wv = (const float*)d_in[5];
  const float* bv = (const float*)d_in[6];
  const float* Wo = (const float*)d_in[7];
  const float* bo = (const float*)d_in[8];
  float* out = (float*)d_out;

  const size_t NX = (size_t)B_ * T_ * C_;  // 4M
  const size_t NW = (size_t)C_ * C_;       // 1M

  u16* xb  = (u16*)d_ws;
  u16* wqb = xb  + NX;        // weights contiguous (qkv GEMM indexes by z)
  u16* wkb = wqb + NW;
  u16* wvb = wkb + NW;
  u16* wob = wvb + NW;
  u16* q   = wob + NW;        // [B,H,T,D], pre-scaled log2-domain
  u16* k   = q   + NX;        // [B,H,T,D]
  u16* v   = k   + NX;        // [B,H,D,T]
  u16* ctx = v   + NX;        // [B,T,C]

  cvt_all<<<dim3((NXF4 + 4 * NWF4) / 256), 256, 0, stream>>>(x, Wq, Wk, Wv, Wo, xb);

  gemm_qkv8<<<dim3(192), 512, 0, stream>>>(xb, wqb, bq, bk, bv, q, k, v);

  attn_flash<<<dim3(512), 256, 0, stream>>>(q, k, v, ctx);

  gemm_out<<<dim3(32, 16), 256, 0, stream>>>(ctx, wob, bo, out);
}

// Round 4
// 183.916 us; speedup vs baseline: 1.0496x; 1.0496x over previous
//
#include <hip/hip_runtime.h>
#include <hip/hip_bf16.h>

#define B_ 2
#define T_ 2048
#define C_ 1024
#define H_ 16
#define D_ 64

typedef unsigned short u16;
typedef __bf16 bf16x8 __attribute__((ext_vector_type(8)));
typedef float floatx4 __attribute__((ext_vector_type(4)));

__device__ __forceinline__ float bf2f(u16 u) {
  union { unsigned int i; float f; } x; x.i = ((unsigned int)u) << 16; return x.f;
}
__device__ __forceinline__ u16 f2bf(float f) {  // RNE
  union { float f; unsigned int i; } x; x.f = f;
  unsigned int r = x.i + 0x7fffu + ((x.i >> 16) & 1u);
  return (u16)(r >> 16);
}

// packed f32x2 -> bf16x2 (RTNE), lo = src0
__device__ __forceinline__ unsigned cvtpk(float lo, float hi) {
  unsigned r;
  asm("v_cvt_pk_bf16_f32 %0, %1, %2" : "=v"(r) : "v"(lo), "v"(hi));
  return r;
}

// async 16B global -> LDS (wave-uniform base + lane*16)
__device__ __forceinline__ void gld16(void* lds, const void* g) {
  __builtin_amdgcn_global_load_lds(
      (const __attribute__((address_space(1))) unsigned int*)g,
      (__attribute__((address_space(3))) unsigned int*)lds, 16, 0, 0);
}

// ---------------------------------------------------------------------------
// Fused fp32 -> bf16 convert for x + 4 weights (one dispatch).
// ---------------------------------------------------------------------------
#define NXF4 1048576   // (B*T*C)/4
#define NWF4 262144    // (C*C)/4

__global__ __launch_bounds__(256) void cvt_all(
    const float* __restrict__ x,  const float* __restrict__ Wq,
    const float* __restrict__ Wk, const float* __restrict__ Wv,
    const float* __restrict__ Wo, u16* __restrict__ dst_base)
{
  const int i = blockIdx.x * 256 + threadIdx.x;
  const float* src; size_t off;
  if (i < NXF4)               { src = x;  off = i; }
  else if (i < NXF4 + NWF4)   { src = Wq; off = i - NXF4; }
  else if (i < NXF4 + 2*NWF4) { src = Wk; off = i - (NXF4 + NWF4); }
  else if (i < NXF4 + 3*NWF4) { src = Wv; off = i - (NXF4 + 2*NWF4); }
  else                        { src = Wo; off = i - (NXF4 + 3*NWF4); }
  float4 f = ((const float4*)src)[off];
  ushort4 o;
  o.x = f2bf(f.x); o.y = f2bf(f.y); o.z = f2bf(f.z); o.w = f2bf(f.w);
  ((ushort4*)dst_base)[i] = o;
}

// ---------------------------------------------------------------------------
// Fused QKV GEMM, 256x256 tile, BK=64, 8-phase counted-vmcnt schedule
// (T1 XCD-partition + T2 XOR-swizzle + T3/T4 8-phase counted vmcnt + T5
//  setprio). One N=3072 GEMM; each 256-wide N-tile lies entirely inside
//  Q (by 0-3), K (by 4-7) or V (by 8-11).
// ---------------------------------------------------------------------------
#define QSCALE 0.1803368801111f  // 0.125 / ln(2)

#define MFMA16(MH, NH, BREG)                                                  \
  do {                                                                        \
    __builtin_amdgcn_s_setprio(1);                                            \
    _Pragma("unroll")                                                         \
    for (int f = 0; f < 4; ++f) {                                             \
      _Pragma("unroll")                                                       \
      for (int g = 0; g < 2; ++g) {                                           \
        acc[(MH)*4 + f][(NH)*2 + g] = __builtin_amdgcn_mfma_f32_16x16x32_bf16(\
            a[f][0], BREG[g][0], acc[(MH)*4 + f][(NH)*2 + g], 0, 0, 0);       \
        acc[(MH)*4 + f][(NH)*2 + g] = __builtin_amdgcn_mfma_f32_16x16x32_bf16(\
            a[f][1], BREG[g][1], acc[(MH)*4 + f][(NH)*2 + g], 0, 0, 0);       \
      }                                                                       \
    }                                                                         \
    __builtin_amdgcn_s_setprio(0);                                            \
  } while (0)

#define PBAR()                                                \
  do {                                                        \
    asm volatile("" ::: "memory");                            \
    __builtin_amdgcn_s_barrier();                             \
    asm volatile("s_waitcnt lgkmcnt(0)" ::: "memory");        \
  } while (0)

#define EBAR()                                                \
  do {                                                        \
    asm volatile("" ::: "memory");                            \
    __builtin_amdgcn_s_barrier();                             \
    asm volatile("" ::: "memory");                            \
  } while (0)

__global__ __launch_bounds__(512, 2) void gemm_qkv8(
    const u16* __restrict__ X, const u16* __restrict__ Wb,
    const float* __restrict__ b0, const float* __restrict__ b1,
    const float* __restrict__ b2,
    u16* __restrict__ Yq, u16* __restrict__ Yk, u16* __restrict__ Yv)
{
  __shared__ __align__(16) u16 L[65536];  // 128 KiB

  const int tid  = threadIdx.x;
  const int lane = tid & 63;
  const int m16  = lane & 15;
  const int q4   = lane >> 4;
  const int wv   = tid >> 6;
  const int wm   = wv >> 2;   // 0..1 : A-half / 128-row slab
  const int wn   = wv & 3;    // 0..3 : 64-col slab

  // XCD-bijective mapping: xcd = bid%8 (round-robin dispatch); each XCD
  // owns a 4x6 (bx,by) sub-grid -> A 2MB + B 3MB working set per L2.
  const int bid = blockIdx.x;
  const int xcd = bid & 7;
  const int idx = bid >> 3;            // 0..23
  const int bx  = (xcd & 3) * 4 + (idx & 3);   // 0..15
  const int by  = (xcd >> 2) * 6 + (idx >> 2); // 0..11

  const u16* Abase  = X  + (size_t)bx * 256 * C_;
  const u16* Bbase  = Wb + (size_t)by * 256 * C_;
  const u16* A1base = Abase + (size_t)128 * C_;
  const u16* B1base = Bbase + (size_t)128 * C_;

  // staging decomposition: phys byte = s*16, s = r*512+tid; row=s>>3,
  // slot16=s&7; content k16 = slot16 ^ (row&7)  (pre-swizzled source)
  const int s0 = tid,       r0 = s0 >> 3;
  const int s1 = tid + 512, r1 = s1 >> 3;
  const int k0a = ((s0 & 7) ^ (r0 & 7)) * 8;
  const int k1a = ((s1 & 7) ^ (r1 & 7)) * 8;

#define STAGE(dsthalf, srcrows, kofs)                                         \
  do {                                                                        \
    gld16(&(dsthalf)[s0 * 8], (srcrows) + (size_t)r0 * C_ + (kofs) + k0a);    \
    gld16(&(dsthalf)[s1 * 8], (srcrows) + (size_t)r1 * C_ + (kofs) + k1a);    \
  } while (0)

  u16* buf0 = L;
  u16* buf1 = L + 32768;
  // half offsets (u16): A0=0  A1=8192  B0=16384  B1=24576

  // prologue: T0 complete + T1{B0,A0} in flight
  STAGE(buf0 + 16384, Bbase, 0);
  STAGE(buf0,         Abase, 0);
  STAGE(buf0 + 24576, B1base, 0);
  STAGE(buf0 + 8192,  A1base, 0);
  STAGE(buf1 + 16384, Bbase, 64);
  STAGE(buf1,         Abase, 64);
  asm volatile("s_waitcnt vmcnt(4)" ::: "memory");
  __builtin_amdgcn_s_barrier();
  asm volatile("" ::: "memory");

  floatx4 acc[8][4] = {};

  // ds_read swizzled k-slot offsets (row&7 == lane&7 for all frag rows)
  const int a0off = m16 * 64 + ((q4      ^ (lane & 7)) * 8);  // k-chunk 0
  const int a1off = m16 * 64 + (((q4 + 4) ^ (lane & 7)) * 8); // k-chunk 1
  const int bro   = (wn & 1) * 4096;  // row offset inside wave's B-half

  for (int i = 0; i < 16; ++i) {
    u16* buf  = (i & 1) ? buf1 : buf0;
    u16* bufn = (i & 1) ? buf0 : buf1;
    const u16* Ah = buf + wm * 8192;
    const u16* Bh = buf + 16384 + (wn >> 1) * 8192;
    const bool p1 = (i + 1) < 16;
    const bool p2 = (i + 2) < 16;
    const int  k1 = (i + 1) * 64;
    const int  k2 = (i + 2) * 64;

    bf16x8 a[4][2], bA[2][2], bB[2][2];

    // ---- phase 0: (mh0, nh0) — 12 ds_reads ----
#pragma unroll
    for (int f = 0; f < 4; ++f) {
      a[f][0] = *(const bf16x8*)&Ah[f * 1024 + a0off];
      a[f][1] = *(const bf16x8*)&Ah[f * 1024 + a1off];
    }
#pragma unroll
    for (int g = 0; g < 2; ++g) {
      bA[g][0] = *(const bf16x8*)&Bh[bro + g * 1024 + a0off];
      bA[g][1] = *(const bf16x8*)&Bh[bro + g * 1024 + a1off];
    }
    if (p1) STAGE(bufn + 24576, B1base, k1);
    PBAR();
    MFMA16(0, 0, bA);
    EBAR();

    // ---- phase 1: (mh0, nh1) — 4 ds_reads ----
#pragma unroll
    for (int g = 0; g < 2; ++g) {
      bB[g][0] = *(const bf16x8*)&Bh[bro + 2048 + g * 1024 + a0off];
      bB[g][1] = *(const bf16x8*)&Bh[bro + 2048 + g * 1024 + a1off];
    }
    if (p1) STAGE(bufn + 8192, A1base, k1);
    PBAR();
    MFMA16(0, 1, bB);
    EBAR();

    // ---- phase 2: (mh1, nh1) — 8 ds_reads ----
#pragma unroll
    for (int f = 0; f < 4; ++f) {
      a[f][0] = *(const bf16x8*)&Ah[4096 + f * 1024 + a0off];
      a[f][1] = *(const bf16x8*)&Ah[4096 + f * 1024 + a1off];
    }
    if (p2) STAGE(buf + 16384, Bbase, k2);   // B reads of this tile done
    PBAR();
    MFMA16(1, 1, bB);
    EBAR();

    // ---- phase 3: (mh1, nh0) — no ds_reads ----
    if (p2) STAGE(buf, Abase, k2);           // A reads of this tile done
    PBAR();
    MFMA16(1, 0, bA);
    asm volatile("" ::: "memory");
    if (p2) asm volatile("s_waitcnt vmcnt(4)" ::: "memory");
    else    asm volatile("s_waitcnt vmcnt(0)" ::: "memory");
    __builtin_amdgcn_s_barrier();
    asm volatile("" ::: "memory");
  }

  // ---- epilogue ----
  const int z    = by >> 2;                       // 0=Q 1=K 2=V
  const int nloc = (by & 3) * 256 + wn * 64;      // n within the z-matrix
  const float* bias = (z == 0) ? b0 : (z == 1) ? b1 : b2;
  const int mbase = bx * 256 + wm * 128 + q4 * 4;

  if (z == 2) {
    // V -> [B,H,D,T]; 4 consecutive t per thread => ushort4 stores
#pragma unroll
    for (int nf = 0; nf < 4; ++nf) {
      const int nz = nloc + nf * 16 + m16;
      const float bv = bias[nz];
      const int h = nz >> 6, d = nz & (D_ - 1);
#pragma unroll
      for (int mf = 0; mf < 8; ++mf) {
        const int m  = mbase + mf * 16;
        const int bb = m >> 11, t = m & (T_ - 1);
        ushort4 pk;
        pk.x = f2bf(acc[mf][nf][0] + bv);
        pk.y = f2bf(acc[mf][nf][1] + bv);
        pk.z = f2bf(acc[mf][nf][2] + bv);
        pk.w = f2bf(acc[mf][nf][3] + bv);
        *(ushort4*)&Yv[(((size_t)bb * H_ + h) * D_ + d) * T_ + t] = pk;
      }
    }
  } else {
    // Q/K -> [B,H,T,D]
    u16* Y = z ? Yk : Yq;
    const float sc = z ? 1.0f : QSCALE;
#pragma unroll
    for (int nf = 0; nf < 4; ++nf) {
      const int nz = nloc + nf * 16 + m16;
      const float bv = bias[nz];
      const int h = nz >> 6, d = nz & (D_ - 1);
#pragma unroll
      for (int mf = 0; mf < 8; ++mf) {
        const int m  = mbase + mf * 16;
        const int bb = m >> 11, tq = m & (T_ - 1);
#pragma unroll
        for (int r = 0; r < 4; ++r) {
          Y[(((size_t)bb * H_ + h) * T_ + (tq + r)) * D_ + d] =
              f2bf((acc[mf][nf][r] + bv) * sc);
        }
      }
    }
  }
}

// ---------------------------------------------------------------------------
// Output projection GEMM (round-7 proven): 128x64 tile, BK=32, 512 blocks.
// ---------------------------------------------------------------------------
__global__ __launch_bounds__(256) void gemm_out(
    const u16* __restrict__ X, const u16* __restrict__ W,
    const float* __restrict__ bias, float* __restrict__ Yf)
{
  const int K = C_, N = C_;
  __shared__ __align__(16) u16 As[128 * 32];  // 8 KB
  __shared__ __align__(16) u16 Bs[64 * 32];   // 4 KB

  const int tid  = threadIdx.x;
  const int wv   = tid >> 6;
  const int lane = tid & 63;
  const int mcol = lane & 15;
  const int quad = lane >> 4;
  const int wr = wv >> 1, wc = wv & 1;
  const int m0 = blockIdx.x * 128;
  const int n0 = blockIdx.y * 64;

  const int srow = tid >> 2;
  const int scol = (tid & 3) * 8;
  const u16* xp0 = X + (size_t)(m0 + srow) * K + scol;
  const u16* xp1 = xp0 + (size_t)64 * K;
  const u16* wp  = W + (size_t)(n0 + srow) * K + scol;

  floatx4 acc[4][2] = {};

  for (int k0 = 0; k0 < K; k0 += 32) {
    gld16(&As[tid * 8],        xp0 + k0);
    gld16(&As[2048 + tid * 8], xp1 + k0);
    gld16(&Bs[tid * 8],        wp + k0);
    __syncthreads();

    bf16x8 a[4], b[2];
#pragma unroll
    for (int rf = 0; rf < 4; ++rf)
      a[rf] = *(const bf16x8*)&As[(wr * 64 + rf * 16 + mcol) * 32 + quad * 8];
#pragma unroll
    for (int cf = 0; cf < 2; ++cf)
      b[cf] = *(const bf16x8*)&Bs[(wc * 32 + cf * 16 + mcol) * 32 + quad * 8];
#pragma unroll
    for (int rf = 0; rf < 4; ++rf)
#pragma unroll
      for (int cf = 0; cf < 2; ++cf)
        acc[rf][cf] = __builtin_amdgcn_mfma_f32_16x16x32_bf16(
            a[rf], b[cf], acc[rf][cf], 0, 0, 0);
    __syncthreads();
  }

#pragma unroll
  for (int cf = 0; cf < 2; ++cf) {
    const int n = n0 + wc * 32 + cf * 16 + mcol;
    const float bv = bias[n];
#pragma unroll
    for (int rf = 0; rf < 4; ++rf) {
#pragma unroll
      for (int r = 0; r < 4; ++r) {
        const int m = m0 + wr * 64 + rf * 16 + quad * 4 + r;
        Yf[(size_t)m * N + n] = acc[rf][cf][r] + bv;
      }
    }
  }
}

// ---------------------------------------------------------------------------
// MFMA flash attention, causal, fixed-base softmax (log2 domain), l via
// ones-row MFMA, K/V double-buffered, swapped QK^T + in-register P rebuild
// (cvt_pk + permlane chain). QBLK=64, 4 waves/block (round-2 proven base).
//
// This revision: K-SPLIT CHUNKING to kill the occupancy-decay tail.
// Round-2 PMC: Occupancy 23% == time-avg of 4-blocks/CU decaying as short
// blocks finish with no backfill (per-CU work 66 iters vs longest block 32).
// Fixed-base softmax => partials combine by PURE ADDITION (no max rescale):
//   q-tiles with iq >= 16 split into chunk0 (k-tiles 0..15) and chunk1
//   (16..iq); each writes unnormalized f32 O-partial (64x64) + l-partial
//   (64, from the ones-row MFMA) to workspace; attn_merge combines.
// Grid 1536, max 16 iters/block, dispatched longest-first (t ascending);
// shortest 512 blocks backfill. XCD invariant: bh = bx&31 => bx==bh mod 8.
//   t = bx>>5 in 0..47:  iq = (t<16) ? 31-t : 47-t
//   t <16 : chunk0  j0=0  j1=15   (partial, iq in 16..31)
//   t 16..31: chunk1 j0=16 j1=iq  (partial, diagonal tile => mask)
//   t >=32: unsplit j0=0  j1=iq   (direct store, iq in 0..15)
// ---------------------------------------------------------------------------
#define KSB 4096   // u16 elems per Ks buffer (64*64)
#define VTB 5120   // u16 elems per Vt buffer (80*64; rows 64..79 = ones/zeros)

__global__ __launch_bounds__(256, 4) void attn_flash(
    const u16* __restrict__ Q, const u16* __restrict__ K,
    const u16* __restrict__ Vg, u16* __restrict__ O,
    float* __restrict__ OP, float* __restrict__ LP)
{
  __shared__ __align__(16) u16 Ks[2 * KSB];     // 16 KB
  __shared__ __align__(16) u16 Vt[2 * VTB];     // 20 KB

  const int tid  = threadIdx.x;
  const int wv   = tid >> 6;
  const int lane = tid & 63;
  const int mcol = lane & 15;
  const int quad = lane >> 4;

  const int bx = blockIdx.x;
  const int bh = bx & 31;             // XCD-partition invariant
  const int t  = bx >> 5;             // 0..47, longest chunks first
  const int iq = (t < 16) ? 31 - t : 47 - t;
  const bool pc = (t < 32);           // partial-write mode
  const int j0 = (t >= 16 && t < 32) ? 16 : 0;
  const int j1 = (t < 16) ? 15 : iq;
  const int ti = pc ? ((bh * 16 + (iq - 16)) * 2 + (j0 ? 1 : 0)) : 0;

  const size_t base  = (size_t)bh * T_ * D_;
  const size_t vbase = (size_t)bh * D_ * T_;
  const int b = bh >> 4, h = bh & (H_ - 1);

  // ones rows in BOTH Vt buffers (rows 64..79; staging only touches 0..63)
  for (int idx = tid; idx < 16 * 64; idx += 256) {
    const u16 val = (idx < 64) ? (u16)0x3F80 : (u16)0;
    Vt[64 * 64 + idx]       = val;
    Vt[VTB + 64 * 64 + idx] = val;
  }

  const int srow = lane >> 3;
  const int sg   = (lane & 7) ^ srow;
  const int c0 = wv * 2, c1 = wv * 2 + 1;
  const int sl0 = (quad ^ (mcol & 7)) * 8;

  const size_t koff0 = base + (size_t)(c0 * 8 + srow) * D_ + sg * 8;
  const size_t koff1 = base + (size_t)(c1 * 8 + srow) * D_ + sg * 8;
  const size_t voff0 = vbase + (size_t)(c0 * 8 + srow) * T_ + sg * 8;
  const size_t voff1 = vbase + (size_t)(c1 * 8 + srow) * T_ + sg * 8;

  const u16* qg = Q + base + (size_t)(iq * 64 + wv * 16 + mcol) * D_ + quad * 8;
  const bf16x8 qf0 = *(const bf16x8*)qg;
  const bf16x8 qf1 = *(const bf16x8*)(qg + 32);

  floatx4 oacc[5] = {};   // [0..3] D-cols; [4] rowsum via ones-row

  // ones-row init visible to all waves, then stage j0 into buffer 0
  __syncthreads();
  {
    const size_t kj = (size_t)j0 * 64 * D_;
    const int    vj = j0 * 64;
    gld16(&Ks[c0 * 512 + lane * 8], K  + koff0 + kj);
    gld16(&Ks[c1 * 512 + lane * 8], K  + koff1 + kj);
    gld16(&Vt[c0 * 512 + lane * 8], Vg + voff0 + vj);
    gld16(&Vt[c1 * 512 + lane * 8], Vg + voff1 + vj);
  }

  for (int j = j0; j <= j1; ++j) {
    const int cur = (j - j0) & 1;
    __syncthreads();   // drains vmcnt(0): buffer `cur` ready

    if (j < j1) {      // prefetch j+1 into the other buffer
      const int nb = cur ^ 1;
      const size_t kj = (size_t)(j + 1) * 64 * D_;
      const int    vj = (j + 1) * 64;
      gld16(&Ks[nb * KSB + c0 * 512 + lane * 8], K  + koff0 + kj);
      gld16(&Ks[nb * KSB + c1 * 512 + lane * 8], K  + koff1 + kj);
      gld16(&Vt[nb * VTB + c0 * 512 + lane * 8], Vg + voff0 + vj);
      gld16(&Vt[nb * VTB + c1 * 512 + lane * 8], Vg + voff1 + vj);
    }

    const u16* ksb = &Ks[cur * KSB];
    const u16* vtb = &Vt[cur * VTB];

    // SWAPPED QK^T: sacc[nt][r] = S[q=mcol][k = nt*16 + quad*4 + r]
    floatx4 sacc[4] = {};
#pragma unroll
    for (int nt = 0; nt < 4; ++nt) {
      const u16* kr = &ksb[(nt * 16 + mcol) * 64];
      bf16x8 kb0 = *(const bf16x8*)&kr[sl0];
      bf16x8 kb1 = *(const bf16x8*)&kr[sl0 ^ 32];
      sacc[nt] = __builtin_amdgcn_mfma_f32_16x16x32_bf16(kb0, qf0, sacc[nt], 0, 0, 0);
      sacc[nt] = __builtin_amdgcn_mfma_f32_16x16x32_bf16(kb1, qf1, sacc[nt], 0, 0, 0);
    }

    if (j == iq) {     // causal: mask k_local > q_local (diagonal tile only)
      const int ql = wv * 16 + mcol;
#pragma unroll
      for (int nt = 0; nt < 4; ++nt) {
#pragma unroll
        for (int r = 0; r < 4; ++r)
          if (nt * 16 + quad * 4 + r > ql) sacc[nt][r] = -1e30f;
      }
    }

    // exp2 + pack pairs: W[nt][i] = {bf(p[2i]), bf(p[2i+1])}
    unsigned w0[2], w1[2], w2[2], w3[2];
#pragma unroll
    for (int i = 0; i < 2; ++i) {
      w0[i] = cvtpk(exp2f(sacc[0][2*i]), exp2f(sacc[0][2*i+1]));
      w1[i] = cvtpk(exp2f(sacc[1][2*i]), exp2f(sacc[1][2*i+1]));
      w2[i] = cvtpk(exp2f(sacc[2][2*i]), exp2f(sacc[2][2*i+1]));
      w3[i] = cvtpk(exp2f(sacc[3][2*i]), exp2f(sacc[3][2*i+1]));
    }

    // in-register redistribute -> PV A-frags
    union { unsigned u[4]; bf16x8 v; } pa0u, pa1u;
#pragma unroll
    for (int i = 0; i < 2; ++i) {
      unsigned x = w0[i], y = w1[i];
      asm("v_permlane32_swap_b32 %0, %1" : "+v"(x), "+v"(y));
      asm("v_permlane16_swap_b32 %0, %1" : "+v"(x), "+v"(y));
      pa0u.u[i] = x; pa0u.u[i + 2] = y;
      unsigned x2 = w2[i], y2 = w3[i];
      asm("v_permlane32_swap_b32 %0, %1" : "+v"(x2), "+v"(y2));
      asm("v_permlane16_swap_b32 %0, %1" : "+v"(x2), "+v"(y2));
      pa1u.u[i] = x2; pa1u.u[i + 2] = y2;
    }
    const bf16x8 pa0 = pa0u.v;
    const bf16x8 pa1 = pa1u.v;

#pragma unroll
    for (int dt = 0; dt < 5; ++dt) {
      const u16* vr = &vtb[(dt * 16 + mcol) * 64];
      bf16x8 vb0 = *(const bf16x8*)&vr[sl0];
      bf16x8 vb1 = *(const bf16x8*)&vr[sl0 ^ 32];
      oacc[dt] = __builtin_amdgcn_mfma_f32_16x16x32_bf16(pa0, vb0, oacc[dt], 0, 0, 0);
      oacc[dt] = __builtin_amdgcn_mfma_f32_16x16x32_bf16(pa1, vb1, oacc[dt], 0, 0, 0);
    }
  }

  if (!pc) {
    // direct store (unsplit tiles, iq < 16)
    float invl[4];
#pragma unroll
    for (int r = 0; r < 4; ++r)
      invl[r] = 1.f / __shfl(oacc[4][r], lane & 48);
#pragma unroll
    for (int dt = 0; dt < 4; ++dt) {
      const int c = h * D_ + dt * 16 + mcol;
#pragma unroll
      for (int r = 0; r < 4; ++r) {
        const int tg = iq * 64 + wv * 16 + quad * 4 + r;
        O[((size_t)b * T_ + tg) * C_ + c] = f2bf(oacc[dt][r] * invl[r]);
      }
    }
  } else {
    // partial store: unnormalized f32 O + l (pure-add merge later)
    float* op = OP + (size_t)ti * 4096;
#pragma unroll
    for (int dt = 0; dt < 4; ++dt)
#pragma unroll
      for (int r = 0; r < 4; ++r)
        op[(wv * 16 + quad * 4 + r) * 64 + dt * 16 + mcol] = oacc[dt][r];
    if (mcol == 0) {
#pragma unroll
      for (int r = 0; r < 4; ++r)
        LP[ti * 64 + wv * 16 + quad * 4 + r] = oacc[4][r];
    }
  }
}

// ---------------------------------------------------------------------------
// Merge the two k-chunks of each split q-tile: O = (A+B)/(lA+lB).
// Grid 512 (32 bh x 16 split q-tiles), 256 threads; thread = (row, d-chunk).
// ---------------------------------------------------------------------------
__global__ __launch_bounds__(256) void attn_merge(
    const float* __restrict__ OP, const float* __restrict__ LP,
    u16* __restrict__ O)
{
  const int mb = blockIdx.x;
  const int bh = mb & 31, qt = mb >> 5;     // qt 0..15 -> iq = 16+qt
  const int iq = 16 + qt;
  const int ti0 = (bh * 16 + qt) * 2;
  const int b = bh >> 4, h = bh & (H_ - 1);
  const int row = threadIdx.x >> 2;
  const int dc  = (threadIdx.x & 3) * 16;

  const float l = LP[ti0 * 64 + row] + LP[(ti0 + 1) * 64 + row];
  const float inv = 1.f / l;
  const float* pa = OP + (size_t)ti0 * 4096 + row * 64 + dc;
  const float* pb = pa + 4096;

  const int tg = iq * 64 + row;
  u16* o = O + ((size_t)b * T_ + tg) * C_ + h * D_ + dc;

  u16 tmp[16];
#pragma unroll
  for (int i = 0; i < 4; ++i) {
    const float4 a4 = ((const float4*)pa)[i];
    const float4 b4 = ((const float4*)pb)[i];
    tmp[i*4 + 0] = f2bf((a4.x + b4.x) * inv);
    tmp[i*4 + 1] = f2bf((a4.y + b4.y) * inv);
    tmp[i*4 + 2] = f2bf((a4.z + b4.z) * inv);
    tmp[i*4 + 3] = f2bf((a4.w + b4.w) * inv);
  }
  *(uint4*)&o[0] = *(const uint4*)&tmp[0];
  *(uint4*)&o[8] = *(const uint4*)&tmp[8];
}

// ---------------------------------------------------------------------------
extern "C" void kernel_launch(void* const* d_in, const int* in_sizes, int n_in,
                              void* d_out, int out_size, void* d_ws, size_t ws_size,
                              hipStream_t stream) {
  const float* x  = (const float*)d_in[0];
  const float* Wq = (const float*)d_in[1];
  const float* bq = (const float*)d_in[2];
  const float* Wk = (const float*)d_in[3];
  const float* bk = (const float*)d_in[4];
  const float* Wv = (const float*)d_in[5];
  const float* bv = (const float*)d_in[6];
  const float* Wo = (const float*)d_in[7];
  const float* bo = (const float*)d_in[8];
  float* out = (float*)d_out;

  const size_t NX = (size_t)B_ * T_ * C_;  // 4M
  const size_t NW = (size_t)C_ * C_;       // 1M

  u16* xb  = (u16*)d_ws;
  u16* wqb = xb  + NX;        // weights contiguous (qkv GEMM indexes by z)
  u16* wkb = wqb + NW;
  u16* wvb = wkb + NW;
  u16* wob = wvb + NW;
  u16* q   = wob + NW;        // [B,H,T,D], pre-scaled log2-domain
  u16* k   = q   + NX;        // [B,H,T,D]
  u16* v   = k   + NX;        // [B,H,D,T]
  u16* ctx = v   + NX;        // [B,T,C]
  float* opart = (float*)(ctx + NX);           // 1024 x 64x64 f32 = 16.8 MB
  float* lpart = opart + (size_t)1024 * 4096;  // 1024 x 64 f32

  cvt_all<<<dim3((NXF4 + 4 * NWF4) / 256), 256, 0, stream>>>(x, Wq, Wk, Wv, Wo, xb);

  gemm_qkv8<<<dim3(192), 512, 0, stream>>>(xb, wqb, bq, bk, bv, q, k, v);

  attn_flash<<<dim3(1536), 256, 0, stream>>>(q, k, v, ctx, opart, lpart);

  attn_merge<<<dim3(512), 256, 0, stream>>>(opart, lpart, ctx);

  gemm_out<<<dim3(32, 16), 256, 0, stream>>>(ctx, wob, bo, out);
}

// Round 5
// 181.484 us; speedup vs baseline: 1.0637x; 1.0134x over previous
//
#include <hip/hip_runtime.h>
#include <hip/hip_bf16.h>

#define B_ 2
#define T_ 2048
#define C_ 1024
#define H_ 16
#define D_ 64

typedef unsigned short u16;
typedef __bf16 bf16x8 __attribute__((ext_vector_type(8)));
typedef float floatx4 __attribute__((ext_vector_type(4)));

__device__ __forceinline__ float bf2f(u16 u) {
  union { unsigned int i; float f; } x; x.i = ((unsigned int)u) << 16; return x.f;
}
__device__ __forceinline__ u16 f2bf(float f) {  // RNE
  union { float f; unsigned int i; } x; x.f = f;
  unsigned int r = x.i + 0x7fffu + ((x.i >> 16) & 1u);
  return (u16)(r >> 16);
}

// packed f32x2 -> bf16x2 (RTNE), lo = src0
__device__ __forceinline__ unsigned cvtpk(float lo, float hi) {
  unsigned r;
  asm("v_cvt_pk_bf16_f32 %0, %1, %2" : "=v"(r) : "v"(lo), "v"(hi));
  return r;
}

// async 16B global -> LDS (wave-uniform base + lane*16)
__device__ __forceinline__ void gld16(void* lds, const void* g) {
  __builtin_amdgcn_global_load_lds(
      (const __attribute__((address_space(1))) unsigned int*)g,
      (__attribute__((address_space(3))) unsigned int*)lds, 16, 0, 0);
}

// ---------------------------------------------------------------------------
// Fused fp32 -> bf16 convert for x + 4 weights (one dispatch).
// ---------------------------------------------------------------------------
#define NXF4 1048576   // (B*T*C)/4
#define NWF4 262144    // (C*C)/4

__global__ __launch_bounds__(256) void cvt_all(
    const float* __restrict__ x,  const float* __restrict__ Wq,
    const float* __restrict__ Wk, const float* __restrict__ Wv,
    const float* __restrict__ Wo, u16* __restrict__ dst_base)
{
  const int i = blockIdx.x * 256 + threadIdx.x;
  const float* src; size_t off;
  if (i < NXF4)               { src = x;  off = i; }
  else if (i < NXF4 + NWF4)   { src = Wq; off = i - NXF4; }
  else if (i < NXF4 + 2*NWF4) { src = Wk; off = i - (NXF4 + NWF4); }
  else if (i < NXF4 + 3*NWF4) { src = Wv; off = i - (NXF4 + 2*NWF4); }
  else                        { src = Wo; off = i - (NXF4 + 3*NWF4); }
  float4 f = ((const float4*)src)[off];
  ushort4 o;
  o.x = f2bf(f.x); o.y = f2bf(f.y); o.z = f2bf(f.z); o.w = f2bf(f.w);
  ((ushort4*)dst_base)[i] = o;
}

// ---------------------------------------------------------------------------
// Fused QKV GEMM, 256x192 tile, BK=64, 8-phase counted-vmcnt schedule.
// GRID = 16x16 = 256 blocks = exactly 1 block/CU (round-4 PMC: the old
// 256x256 tiling gave 192 blocks -> 64 CUs idle, Occupancy 12.7%).
// One N=3072 GEMM; 192-wide tiles cross Q/K/V boundaries, but boundaries
// (1024,2048) are multiples of 16 => z uniform per 16-col fragment; the
// epilogue selects z per-nf.
//
// LDS 112 KiB: 2 buffers x { A0[128x64] A1[128x64] B[192x64] }.
// B staged as 3 one-op 64-row units (B0,B1,B2); A as 2 two-op halves.
// Per tile i: ph0 stages T_{i+1}A1, ph1 T_{i+1}B2, ph2 T_{i+2}B0B1 (cur,
// B reads done), ph3 T_{i+2}A0 (cur, A reads done). 7 ops/tile issued,
// boundary s_waitcnt vmcnt(4) == T_{i+1} complete, T_{i+2}{B0B1,A0} in
// flight — identical invariant to the proven 256x256 schedule.
// ---------------------------------------------------------------------------
#define QSCALE 0.1803368801111f  // 0.125 / ln(2)

#define PBAR()                                                \
  do {                                                        \
    asm volatile("" ::: "memory");                            \
    __builtin_amdgcn_s_barrier();                             \
    asm volatile("s_waitcnt lgkmcnt(0)" ::: "memory");        \
  } while (0)

#define EBAR()                                                \
  do {                                                        \
    asm volatile("" ::: "memory");                            \
    __builtin_amdgcn_s_barrier();                             \
    asm volatile("" ::: "memory");                            \
  } while (0)

__global__ __launch_bounds__(512, 2) void gemm_qkv8(
    const u16* __restrict__ X, const u16* __restrict__ Wb,
    const float* __restrict__ b0, const float* __restrict__ b1,
    const float* __restrict__ b2,
    u16* __restrict__ Yq, u16* __restrict__ Yk, u16* __restrict__ Yv)
{
  __shared__ __align__(16) u16 L[57344];  // 112 KiB

  const int tid  = threadIdx.x;
  const int lane = tid & 63;
  const int m16  = lane & 15;
  const int q4   = lane >> 4;
  const int wv   = tid >> 6;
  const int wm   = wv >> 2;   // 0..1 : 128-row A slab
  const int wn   = wv & 3;    // 0..3 : 48-col B slab

  // XCD-bijective: xcd = bid%8; each XCD owns a 4x8 (bx,by) sub-grid
  // -> A 2MB + B 3MB working set per L2.
  const int bid = blockIdx.x;
  const int xcd = bid & 7;
  const int idx = bid >> 3;            // 0..31
  const int bx  = (xcd & 3) * 4 + (idx & 3);   // 0..15
  const int by  = (xcd >> 2) * 8 + (idx >> 2); // 0..15

  const u16* Abase  = X  + (size_t)bx * 256 * C_;
  const u16* Bbase  = Wb + (size_t)by * 192 * C_;
  const u16* A1base = Abase + (size_t)128 * C_;

  // staging: phys slot s (16B) at s*16; row = s>>3, slot16 = s&7,
  // content k16 = slot16 ^ (row&7)  (pre-swizzled source)
  const int rB  = tid >> 3;                 // 0..63
  const int s0 = tid,       r0 = rB;
  const int s1 = tid + 512, r1 = 64 + rB;
  const int k0a = ((tid & 7) ^ (rB & 7)) * 8;   // == k1a (64 ≡ 0 mod 8)

#define STAGE_A(dsthalf, srcrows, kofs)                                       \
  do {                                                                        \
    gld16(&(dsthalf)[s0 * 8], (srcrows) + (size_t)r0 * C_ + (kofs) + k0a);    \
    gld16(&(dsthalf)[s1 * 8], (srcrows) + (size_t)r1 * C_ + (kofs) + k0a);    \
  } while (0)

#define STAGE_BL(dstB, srcrows, kofs, l)                                      \
  gld16(&(dstB)[((l) * 512 + tid) * 8],                                       \
        (srcrows) + (size_t)((l) * 64 + rB) * C_ + (kofs) + k0a)

  u16* buf0 = L;
  u16* buf1 = L + 28672;
  // region offsets (u16): A0=0  A1=8192  B=16384 (192x64)

  // prologue: T0 full (7 ops) + T1 {B0,B1,A0} (4 ops)
  STAGE_BL(buf0 + 16384, Bbase, 0, 0);
  STAGE_BL(buf0 + 16384, Bbase, 0, 1);
  STAGE_BL(buf0 + 16384, Bbase, 0, 2);
  STAGE_A (buf0,         Abase,  0);
  STAGE_A (buf0 + 8192,  A1base, 0);
  STAGE_BL(buf1 + 16384, Bbase, 64, 0);
  STAGE_BL(buf1 + 16384, Bbase, 64, 1);
  STAGE_A (buf1,         Abase, 64);
  asm volatile("s_waitcnt vmcnt(4)" ::: "memory");
  __builtin_amdgcn_s_barrier();
  asm volatile("" ::: "memory");

  floatx4 acc[8][3] = {};

  // ds_read swizzled k-slot offsets (row&7 == lane&7 for all frag rows)
  const int a0off = m16 * 64 + ((q4      ^ (lane & 7)) * 8);  // k-chunk 0
  const int a1off = m16 * 64 + (((q4 + 4) ^ (lane & 7)) * 8); // k-chunk 1
  const int bro   = wn * 3072;   // wave's 48-row B slab (48*64)

  for (int i = 0; i < 16; ++i) {
    u16* buf  = (i & 1) ? buf1 : buf0;
    u16* bufn = (i & 1) ? buf0 : buf1;
    const u16* Ah = buf + wm * 8192;
    const u16* Bh = buf + 16384;
    const bool p1 = (i + 1) < 16;
    const bool p2 = (i + 2) < 16;
    const int  k1 = (i + 1) * 64;
    const int  k2 = (i + 2) * 64;

    bf16x8 a[4][2], bA[2][2], bB[2];

    // ---- phase 0: (mh0, nf0+nf1) — 12 ds_reads, 16 MFMA ----
#pragma unroll
    for (int f = 0; f < 4; ++f) {
      a[f][0] = *(const bf16x8*)&Ah[f * 1024 + a0off];
      a[f][1] = *(const bf16x8*)&Ah[f * 1024 + a1off];
    }
#pragma unroll
    for (int g = 0; g < 2; ++g) {
      bA[g][0] = *(const bf16x8*)&Bh[bro + g * 1024 + a0off];
      bA[g][1] = *(const bf16x8*)&Bh[bro + g * 1024 + a1off];
    }
    if (p1) STAGE_A(bufn + 8192, A1base, k1);
    PBAR();
    __builtin_amdgcn_s_setprio(1);
#pragma unroll
    for (int f = 0; f < 4; ++f)
#pragma unroll
      for (int g = 0; g < 2; ++g) {
        acc[f][g] = __builtin_amdgcn_mfma_f32_16x16x32_bf16(a[f][0], bA[g][0], acc[f][g], 0, 0, 0);
        acc[f][g] = __builtin_amdgcn_mfma_f32_16x16x32_bf16(a[f][1], bA[g][1], acc[f][g], 0, 0, 0);
      }
    __builtin_amdgcn_s_setprio(0);
    EBAR();

    // ---- phase 1: (mh0, nf2) — 2 ds_reads, 8 MFMA ----
    bB[0] = *(const bf16x8*)&Bh[bro + 2048 + a0off];
    bB[1] = *(const bf16x8*)&Bh[bro + 2048 + a1off];
    if (p1) STAGE_BL(bufn + 16384, Bbase, k1, 2);
    PBAR();
    __builtin_amdgcn_s_setprio(1);
#pragma unroll
    for (int f = 0; f < 4; ++f) {
      acc[f][2] = __builtin_amdgcn_mfma_f32_16x16x32_bf16(a[f][0], bB[0], acc[f][2], 0, 0, 0);
      acc[f][2] = __builtin_amdgcn_mfma_f32_16x16x32_bf16(a[f][1], bB[1], acc[f][2], 0, 0, 0);
    }
    __builtin_amdgcn_s_setprio(0);
    EBAR();

    // ---- phase 2: (mh1, nf2) — 8 ds_reads, 8 MFMA ----
#pragma unroll
    for (int f = 0; f < 4; ++f) {
      a[f][0] = *(const bf16x8*)&Ah[4096 + f * 1024 + a0off];
      a[f][1] = *(const bf16x8*)&Ah[4096 + f * 1024 + a1off];
    }
    if (p2) {   // B reads of this tile done
      STAGE_BL(buf + 16384, Bbase, k2, 0);
      STAGE_BL(buf + 16384, Bbase, k2, 1);
    }
    PBAR();
    __builtin_amdgcn_s_setprio(1);
#pragma unroll
    for (int f = 0; f < 4; ++f) {
      acc[4 + f][2] = __builtin_amdgcn_mfma_f32_16x16x32_bf16(a[f][0], bB[0], acc[4 + f][2], 0, 0, 0);
      acc[4 + f][2] = __builtin_amdgcn_mfma_f32_16x16x32_bf16(a[f][1], bB[1], acc[4 + f][2], 0, 0, 0);
    }
    __builtin_amdgcn_s_setprio(0);
    EBAR();

    // ---- phase 3: (mh1, nf0+nf1) — no ds_reads, 16 MFMA ----
    if (p2) STAGE_A(buf, Abase, k2);         // A reads of this tile done
    PBAR();
    __builtin_amdgcn_s_setprio(1);
#pragma unroll
    for (int f = 0; f < 4; ++f)
#pragma unroll
      for (int g = 0; g < 2; ++g) {
        acc[4 + f][g] = __builtin_amdgcn_mfma_f32_16x16x32_bf16(a[f][0], bA[g][0], acc[4 + f][g], 0, 0, 0);
        acc[4 + f][g] = __builtin_amdgcn_mfma_f32_16x16x32_bf16(a[f][1], bA[g][1], acc[4 + f][g], 0, 0, 0);
      }
    __builtin_amdgcn_s_setprio(0);
    asm volatile("" ::: "memory");
    if (p2) asm volatile("s_waitcnt vmcnt(4)" ::: "memory");
    else    asm volatile("s_waitcnt vmcnt(0)" ::: "memory");
    __builtin_amdgcn_s_barrier();
    asm volatile("" ::: "memory");
  }

  // ---- epilogue: z selected per 16-col fragment ----
  const int mbase = bx * 256 + wm * 128 + q4 * 4;
#pragma unroll
  for (int nf = 0; nf < 3; ++nf) {
    const int nzg = by * 192 + wn * 48 + nf * 16 + m16;
    const int z  = nzg >> 10;           // 0=Q 1=K 2=V (uniform in fragment)
    const int nl = nzg & 1023;
    const int h = nl >> 6, d = nl & (D_ - 1);
    const float bv = (z == 0 ? b0 : z == 1 ? b1 : b2)[nl];
    if (z == 2) {
      // V -> [B,H,D,T]; 4 consecutive t per thread => ushort4 stores
#pragma unroll
      for (int mf = 0; mf < 8; ++mf) {
        const int m  = mbase + mf * 16;
        const int bb = m >> 11, t = m & (T_ - 1);
        ushort4 pk;
        pk.x = f2bf(acc[mf][nf][0] + bv);
        pk.y = f2bf(acc[mf][nf][1] + bv);
        pk.z = f2bf(acc[mf][nf][2] + bv);
        pk.w = f2bf(acc[mf][nf][3] + bv);
        *(ushort4*)&Yv[(((size_t)bb * H_ + h) * D_ + d) * T_ + t] = pk;
      }
    } else {
      u16* Y = z ? Yk : Yq;
      const float sc = z ? 1.0f : QSCALE;
#pragma unroll
      for (int mf = 0; mf < 8; ++mf) {
        const int m  = mbase + mf * 16;
        const int bb = m >> 11, tq = m & (T_ - 1);
#pragma unroll
        for (int r = 0; r < 4; ++r) {
          Y[(((size_t)bb * H_ + h) * T_ + (tq + r)) * D_ + d] =
              f2bf((acc[mf][nf][r] + bv) * sc);
        }
      }
    }
  }
}

// ---------------------------------------------------------------------------
// Output projection GEMM (round-7 proven): 128x64 tile, BK=32, 512 blocks.
// ---------------------------------------------------------------------------
__global__ __launch_bounds__(256) void gemm_out(
    const u16* __restrict__ X, const u16* __restrict__ W,
    const float* __restrict__ bias, float* __restrict__ Yf)
{
  const int K = C_, N = C_;
  __shared__ __align__(16) u16 As[128 * 32];  // 8 KB
  __shared__ __align__(16) u16 Bs[64 * 32];   // 4 KB

  const int tid  = threadIdx.x;
  const int wv   = tid >> 6;
  const int lane = tid & 63;
  const int mcol = lane & 15;
  const int quad = lane >> 4;
  const int wr = wv >> 1, wc = wv & 1;
  const int m0 = blockIdx.x * 128;
  const int n0 = blockIdx.y * 64;

  const int srow = tid >> 2;
  const int scol = (tid & 3) * 8;
  const u16* xp0 = X + (size_t)(m0 + srow) * K + scol;
  const u16* xp1 = xp0 + (size_t)64 * K;
  const u16* wp  = W + (size_t)(n0 + srow) * K + scol;

  floatx4 acc[4][2] = {};

  for (int k0 = 0; k0 < K; k0 += 32) {
    gld16(&As[tid * 8],        xp0 + k0);
    gld16(&As[2048 + tid * 8], xp1 + k0);
    gld16(&Bs[tid * 8],        wp + k0);
    __syncthreads();

    bf16x8 a[4], b[2];
#pragma unroll
    for (int rf = 0; rf < 4; ++rf)
      a[rf] = *(const bf16x8*)&As[(wr * 64 + rf * 16 + mcol) * 32 + quad * 8];
#pragma unroll
    for (int cf = 0; cf < 2; ++cf)
      b[cf] = *(const bf16x8*)&Bs[(wc * 32 + cf * 16 + mcol) * 32 + quad * 8];
#pragma unroll
    for (int rf = 0; rf < 4; ++rf)
#pragma unroll
      for (int cf = 0; cf < 2; ++cf)
        acc[rf][cf] = __builtin_amdgcn_mfma_f32_16x16x32_bf16(
            a[rf], b[cf], acc[rf][cf], 0, 0, 0);
    __syncthreads();
  }

#pragma unroll
  for (int cf = 0; cf < 2; ++cf) {
    const int n = n0 + wc * 32 + cf * 16 + mcol;
    const float bv = bias[n];
#pragma unroll
    for (int rf = 0; rf < 4; ++rf) {
#pragma unroll
      for (int r = 0; r < 4; ++r) {
        const int m = m0 + wr * 64 + rf * 16 + quad * 4 + r;
        Yf[(size_t)m * N + n] = acc[rf][cf][r] + bv;
      }
    }
  }
}

// ---------------------------------------------------------------------------
// MFMA flash attention, causal, fixed-base softmax (log2 domain), l via
// ones-row MFMA, K/V double-buffered, swapped QK^T + in-register P rebuild
// (cvt_pk + permlane chain). QBLK=64, 4 waves/block. K-split chunking
// (round-4): q-tiles with iq>=16 split into two chunks writing unnormalized
// f32 partials (pure-add merge; fixed-base softmax needs no max rescale).
// Grid 1536, max 16 iters/block, longest-first; XCD invariant bh = bx&31.
// ---------------------------------------------------------------------------
#define KSB 4096   // u16 elems per Ks buffer (64*64)
#define VTB 5120   // u16 elems per Vt buffer (80*64; rows 64..79 = ones/zeros)

__global__ __launch_bounds__(256, 4) void attn_flash(
    const u16* __restrict__ Q, const u16* __restrict__ K,
    const u16* __restrict__ Vg, u16* __restrict__ O,
    float* __restrict__ OP, float* __restrict__ LP)
{
  __shared__ __align__(16) u16 Ks[2 * KSB];     // 16 KB
  __shared__ __align__(16) u16 Vt[2 * VTB];     // 20 KB

  const int tid  = threadIdx.x;
  const int wv   = tid >> 6;
  const int lane = tid & 63;
  const int mcol = lane & 15;
  const int quad = lane >> 4;

  const int bx = blockIdx.x;
  const int bh = bx & 31;             // XCD-partition invariant
  const int t  = bx >> 5;             // 0..47, longest chunks first
  const int iq = (t < 16) ? 31 - t : 47 - t;
  const bool pc = (t < 32);           // partial-write mode
  const int j0 = (t >= 16 && t < 32) ? 16 : 0;
  const int j1 = (t < 16) ? 15 : iq;
  const int ti = pc ? ((bh * 16 + (iq - 16)) * 2 + (j0 ? 1 : 0)) : 0;

  const size_t base  = (size_t)bh * T_ * D_;
  const size_t vbase = (size_t)bh * D_ * T_;
  const int b = bh >> 4, h = bh & (H_ - 1);

  // ones rows in BOTH Vt buffers (rows 64..79; staging only touches 0..63)
  for (int idx = tid; idx < 16 * 64; idx += 256) {
    const u16 val = (idx < 64) ? (u16)0x3F80 : (u16)0;
    Vt[64 * 64 + idx]       = val;
    Vt[VTB + 64 * 64 + idx] = val;
  }

  const int srow = lane >> 3;
  const int sg   = (lane & 7) ^ srow;
  const int c0 = wv * 2, c1 = wv * 2 + 1;
  const int sl0 = (quad ^ (mcol & 7)) * 8;

  const size_t koff0 = base + (size_t)(c0 * 8 + srow) * D_ + sg * 8;
  const size_t koff1 = base + (size_t)(c1 * 8 + srow) * D_ + sg * 8;
  const size_t voff0 = vbase + (size_t)(c0 * 8 + srow) * T_ + sg * 8;
  const size_t voff1 = vbase + (size_t)(c1 * 8 + srow) * T_ + sg * 8;

  const u16* qg = Q + base + (size_t)(iq * 64 + wv * 16 + mcol) * D_ + quad * 8;
  const bf16x8 qf0 = *(const bf16x8*)qg;
  const bf16x8 qf1 = *(const bf16x8*)(qg + 32);

  floatx4 oacc[5] = {};   // [0..3] D-cols; [4] rowsum via ones-row

  // ones-row init visible to all waves, then stage j0 into buffer 0
  __syncthreads();
  {
    const size_t kj = (size_t)j0 * 64 * D_;
    const int    vj = j0 * 64;
    gld16(&Ks[c0 * 512 + lane * 8], K  + koff0 + kj);
    gld16(&Ks[c1 * 512 + lane * 8], K  + koff1 + kj);
    gld16(&Vt[c0 * 512 + lane * 8], Vg + voff0 + vj);
    gld16(&Vt[c1 * 512 + lane * 8], Vg + voff1 + vj);
  }

  for (int j = j0; j <= j1; ++j) {
    const int cur = (j - j0) & 1;
    __syncthreads();   // drains vmcnt(0): buffer `cur` ready

    if (j < j1) {      // prefetch j+1 into the other buffer
      const int nb = cur ^ 1;
      const size_t kj = (size_t)(j + 1) * 64 * D_;
      const int    vj = (j + 1) * 64;
      gld16(&Ks[nb * KSB + c0 * 512 + lane * 8], K  + koff0 + kj);
      gld16(&Ks[nb * KSB + c1 * 512 + lane * 8], K  + koff1 + kj);
      gld16(&Vt[nb * VTB + c0 * 512 + lane * 8], Vg + voff0 + vj);
      gld16(&Vt[nb * VTB + c1 * 512 + lane * 8], Vg + voff1 + vj);
    }

    const u16* ksb = &Ks[cur * KSB];
    const u16* vtb = &Vt[cur * VTB];

    // SWAPPED QK^T: sacc[nt][r] = S[q=mcol][k = nt*16 + quad*4 + r]
    floatx4 sacc[4] = {};
#pragma unroll
    for (int nt = 0; nt < 4; ++nt) {
      const u16* kr = &ksb[(nt * 16 + mcol) * 64];
      bf16x8 kb0 = *(const bf16x8*)&kr[sl0];
      bf16x8 kb1 = *(const bf16x8*)&kr[sl0 ^ 32];
      sacc[nt] = __builtin_amdgcn_mfma_f32_16x16x32_bf16(kb0, qf0, sacc[nt], 0, 0, 0);
      sacc[nt] = __builtin_amdgcn_mfma_f32_16x16x32_bf16(kb1, qf1, sacc[nt], 0, 0, 0);
    }

    if (j == iq) {     // causal: mask k_local > q_local (diagonal tile only)
      const int ql = wv * 16 + mcol;
#pragma unroll
      for (int nt = 0; nt < 4; ++nt) {
#pragma unroll
        for (int r = 0; r < 4; ++r)
          if (nt * 16 + quad * 4 + r > ql) sacc[nt][r] = -1e30f;
      }
    }

    // exp2 + pack pairs: W[nt][i] = {bf(p[2i]), bf(p[2i+1])}
    unsigned w0[2], w1[2], w2[2], w3[2];
#pragma unroll
    for (int i = 0; i < 2; ++i) {
      w0[i] = cvtpk(exp2f(sacc[0][2*i]), exp2f(sacc[0][2*i+1]));
      w1[i] = cvtpk(exp2f(sacc[1][2*i]), exp2f(sacc[1][2*i+1]));
      w2[i] = cvtpk(exp2f(sacc[2][2*i]), exp2f(sacc[2][2*i+1]));
      w3[i] = cvtpk(exp2f(sacc[3][2*i]), exp2f(sacc[3][2*i+1]));
    }

    // in-register redistribute -> PV A-frags
    union { unsigned u[4]; bf16x8 v; } pa0u, pa1u;
#pragma unroll
    for (int i = 0; i < 2; ++i) {
      unsigned x = w0[i], y = w1[i];
      asm("v_permlane32_swap_b32 %0, %1" : "+v"(x), "+v"(y));
      asm("v_permlane16_swap_b32 %0, %1" : "+v"(x), "+v"(y));
      pa0u.u[i] = x; pa0u.u[i + 2] = y;
      unsigned x2 = w2[i], y2 = w3[i];
      asm("v_permlane32_swap_b32 %0, %1" : "+v"(x2), "+v"(y2));
      asm("v_permlane16_swap_b32 %0, %1" : "+v"(x2), "+v"(y2));
      pa1u.u[i] = x2; pa1u.u[i + 2] = y2;
    }
    const bf16x8 pa0 = pa0u.v;
    const bf16x8 pa1 = pa1u.v;

#pragma unroll
    for (int dt = 0; dt < 5; ++dt) {
      const u16* vr = &vtb[(dt * 16 + mcol) * 64];
      bf16x8 vb0 = *(const bf16x8*)&vr[sl0];
      bf16x8 vb1 = *(const bf16x8*)&vr[sl0 ^ 32];
      oacc[dt] = __builtin_amdgcn_mfma_f32_16x16x32_bf16(pa0, vb0, oacc[dt], 0, 0, 0);
      oacc[dt] = __builtin_amdgcn_mfma_f32_16x16x32_bf16(pa1, vb1, oacc[dt], 0, 0, 0);
    }
  }

  if (!pc) {
    // direct store (unsplit tiles, iq < 16)
    float invl[4];
#pragma unroll
    for (int r = 0; r < 4; ++r)
      invl[r] = 1.f / __shfl(oacc[4][r], lane & 48);
#pragma unroll
    for (int dt = 0; dt < 4; ++dt) {
      const int c = h * D_ + dt * 16 + mcol;
#pragma unroll
      for (int r = 0; r < 4; ++r) {
        const int tg = iq * 64 + wv * 16 + quad * 4 + r;
        O[((size_t)b * T_ + tg) * C_ + c] = f2bf(oacc[dt][r] * invl[r]);
      }
    }
  } else {
    // partial store: unnormalized f32 O + l (pure-add merge later)
    float* op = OP + (size_t)ti * 4096;
#pragma unroll
    for (int dt = 0; dt < 4; ++dt)
#pragma unroll
      for (int r = 0; r < 4; ++r)
        op[(wv * 16 + quad * 4 + r) * 64 + dt * 16 + mcol] = oacc[dt][r];
    if (mcol == 0) {
#pragma unroll
      for (int r = 0; r < 4; ++r)
        LP[ti * 64 + wv * 16 + quad * 4 + r] = oacc[4][r];
    }
  }
}

// ---------------------------------------------------------------------------
// Merge the two k-chunks of each split q-tile: O = (A+B)/(lA+lB).
// Grid 512 (32 bh x 16 split q-tiles), 256 threads; thread = (row, d-chunk).
// ---------------------------------------------------------------------------
__global__ __launch_bounds__(256) void attn_merge(
    const float* __restrict__ OP, const float* __restrict__ LP,
    u16* __restrict__ O)
{
  const int mb = blockIdx.x;
  const int bh = mb & 31, qt = mb >> 5;     // qt 0..15 -> iq = 16+qt
  const int iq = 16 + qt;
  const int ti0 = (bh * 16 + qt) * 2;
  const int b = bh >> 4, h = bh & (H_ - 1);
  const int row = threadIdx.x >> 2;
  const int dc  = (threadIdx.x & 3) * 16;

  const float l = LP[ti0 * 64 + row] + LP[(ti0 + 1) * 64 + row];
  const float inv = 1.f / l;
  const float* pa = OP + (size_t)ti0 * 4096 + row * 64 + dc;
  const float* pb = pa + 4096;

  const int tg = iq * 64 + row;
  u16* o = O + ((size_t)b * T_ + tg) * C_ + h * D_ + dc;

  u16 tmp[16];
#pragma unroll
  for (int i = 0; i < 4; ++i) {
    const float4 a4 = ((const float4*)pa)[i];
    const float4 b4 = ((const float4*)pb)[i];
    tmp[i*4 + 0] = f2bf((a4.x + b4.x) * inv);
    tmp[i*4 + 1] = f2bf((a4.y + b4.y) * inv);
    tmp[i*4 + 2] = f2bf((a4.z + b4.z) * inv);
    tmp[i*4 + 3] = f2bf((a4.w + b4.w) * inv);
  }
  *(uint4*)&o[0] = *(const uint4*)&tmp[0];
  *(uint4*)&o[8] = *(const uint4*)&tmp[8];
}

// ---------------------------------------------------------------------------
extern "C" void kernel_launch(void* const* d_in, const int* in_sizes, int n_in,
                              void* d_out, int out_size, void* d_ws, size_t ws_size,
                              hipStream_t stream) {
  const float* x  = (const float*)d_in[0];
  const float* Wq = (const float*)d_in[1];
  const float* bq = (const float*)d_in[2];
  const float* Wk = (const float*)d_in[3];
  const float* bk = (const float*)d_in[4];
  const float* Wv = (const float*)d_in[5];
  const float* bv = (const float*)d_in[6];
  const float* Wo = (const float*)d_in[7];
  const float* bo = (const float*)d_in[8];
  float* out = (float*)d_out;

  const size_t NX = (size_t)B_ * T_ * C_;  // 4M
  const size_t NW = (size_t)C_ * C_;       // 1M

  u16* xb  = (u16*)d_ws;
  u16* wqb = xb  + NX;        // weights contiguous (qkv GEMM indexes by z)
  u16* wkb = wqb + NW;
  u16* wvb = wkb + NW;
  u16* wob = wvb + NW;
  u16* q   = wob + NW;        // [B,H,T,D], pre-scaled log2-domain
  u16* k   = q   + NX;        // [B,H,T,D]
  u16* v   = k   + NX;        // [B,H,D,T]
  u16* ctx = v   + NX;        // [B,T,C]
  float* opart = (float*)(ctx + NX);           // 1024 x 64x64 f32 = 16.8 MB
  float* lpart = opart + (size_t)1024 * 4096;  // 1024 x 64 f32

  cvt_all<<<dim3((NXF4 + 4 * NWF4) / 256), 256, 0, stream>>>(x, Wq, Wk, Wv, Wo, xb);

  gemm_qkv8<<<dim3(256), 512, 0, stream>>>(xb, wqb, bq, bk, bv, q, k, v);

  attn_flash<<<dim3(1536), 256, 0, stream>>>(q, k, v, ctx, opart, lpart);

  attn_merge<<<dim3(512), 256, 0, stream>>>(opart, lpart, ctx);

  gemm_out<<<dim3(32, 16), 256, 0, stream>>>(ctx, wob, bo, out);
}